// Round 6
// baseline (53.411 us; speedup 1.0000x reference)
//
#include <hip/hip_runtime.h>
#include <hip/hip_bf16.h>

// MMD via symmetric triangular chunk decomposition.
// u = [x; w] (16384 pts), s = [-1; +1]:
//   result = (sum_{i,j} s_i s_j k(u_i,u_j)) / 8192^2,   k = exp(-d2/2) = 2^(CEXP*d2)
// Chunks of 256 points, 64 chunks, 2080 (I>=J) chunk-pair blocks; off-diagonal x2.
//
// R6 exp path (fast-math-proof, UB-free; R5's magic-bit split was vulnerable to
// reassociation folding (a+M)-M -> a and to signed-shift UB, either of which
// explains the 1.6e-3 failure vs the 2e-6 mathematical error bound):
//   k = 2^(arg') * E_B,  arg' = fma(ax',bx, fma(ay',by, fma(az',bz, a2c))),
//   E_B = 2^(CEXP*|b|^2) precomputed at staging (folds the per-b add away;
//   accumulate becomes pkfma(e, E_B, acc)).
//   nf = rintf(arg')  [v_rndne_f32 -- nothing for the compiler to fold]
//   r  = arg' - nf    [exact by Sterbenz, r in [-0.5, 0.5]]
//   p  = deg-5 Taylor Horner (rel err <= 2.4e-6, largely cancels in t1-2t2+t3)
//   e  = ldexp(p, (int)nf)  [v_ldexp_f32 -- no bit shifts, any n safe]
// arg' range: CEXP*(d2 - |b|^2) in [-59, +30] -> ldexp always in range.
//
// R4 lesson kept: __launch_bounds__(256,6); (256,8) forced VGPR 32 -> scratch.

#define NPTS   8192
#define CH     256
#define NC     64                  // 16384 / CH
#define NXC    32                  // chunks holding x (first half)
#define NB     2080                // NC*(NC+1)/2
#define BLOCK  256
#define CEXP   (-0.72134752044448169f)     // -1/(2 ln 2)
#define M2CEXP (1.44269504088896340736f)   // -2*CEXP = 1/ln2

typedef float f32x2 __attribute__((ext_vector_type(2)));
typedef float f32x4 __attribute__((ext_vector_type(4)));

__device__ __forceinline__ f32x2 pkfma(f32x2 a, f32x2 b, f32x2 c) {
#if __has_builtin(__builtin_elementwise_fma)
    return __builtin_elementwise_fma(a, b, c);
#else
    f32x2 r; r.x = fmaf(a.x, b.x, c.x); r.y = fmaf(a.y, b.y, c.y); return r;
#endif
}

__device__ __forceinline__ float hw_ldexp(float v, int n) {
#if __has_builtin(__builtin_amdgcn_ldexpf)
    return __builtin_amdgcn_ldexpf(v, n);
#else
    return ldexpf(v, n);
#endif
}

#define PK2(v) ((f32x2){(v), (v)})

// acc += 2^a * eb, packed pair. a in [-59, +30].
__device__ __forceinline__ f32x2 pk_exp2_mul_acc(f32x2 a, f32x2 eb, f32x2 acc) {
    float n0 = rintf(a.x);                     // v_rndne_f32
    float n1 = rintf(a.y);
    f32x2 nf = { n0, n1 };
    f32x2 r  = a - nf;                         // exact (Sterbenz), in [-0.5, 0.5]
    f32x2 p  = PK2(0.0013333558f);             // ln2^5/120
    p = pkfma(p, r, PK2(0.0096181291f));       // ln2^4/24
    p = pkfma(p, r, PK2(0.0555041087f));       // ln2^3/6
    p = pkfma(p, r, PK2(0.2402265070f));       // ln2^2/2
    p = pkfma(p, r, PK2(0.6931471806f));       // ln2
    p = pkfma(p, r, PK2(1.0f));
    f32x2 e;
    e.x = hw_ldexp(p.x, (int)n0);              // v_cvt_i32_f32 (exact) + v_ldexp_f32
    e.y = hw_ldexp(p.y, (int)n1);
    return pkfma(e, eb, acc);
}

__global__ __launch_bounds__(BLOCK, 6) void mmd_tri(const float* __restrict__ x,
                                                    const float* __restrict__ w,
                                                    float* __restrict__ partials) {
    __shared__ f32x4  sAX[CH/4], sAY[CH/4], sAZ[CH/4], sA2[CH/4];  // A-form SoA
    __shared__ float4 sB[CH];                  // (bx, by, bz, E_B=2^(C|b|^2))
    __shared__ float  red[4];

    // blockIdx -> lower-triangle chunk pair (I, J), J <= I
    const int bid = blockIdx.x;
    int I = (int)((sqrtf(8.0f * (float)bid + 1.0f) - 1.0f) * 0.5f);
    while ((I + 1) * (I + 2) / 2 <= bid) ++I;
    while (I * (I + 1) / 2 > bid) --I;
    const int J = bid - I * (I + 1) / 2;

    const int tid = threadIdx.x;
    {
        int gi = I * CH + tid;                      // chunks never straddle x/w
        const float* s = (gi < NPTS) ? x : w;
        int ii = gi & (NPTS - 1);
        float px = s[3*ii], py = s[3*ii+1], pz = s[3*ii+2];
        ((float*)sAX)[tid] = M2CEXP * px;
        ((float*)sAY)[tid] = M2CEXP * py;
        ((float*)sAZ)[tid] = M2CEXP * pz;
        ((float*)sA2)[tid] = CEXP * (px*px + py*py + pz*pz);

        int gj = J * CH + tid;
        const float* t = (gj < NPTS) ? x : w;
        int jj = gj & (NPTS - 1);
        float qx = t[3*jj], qy = t[3*jj+1], qz = t[3*jj+2];
        sB[tid] = make_float4(qx, qy, qz,
                              exp2f(CEXP * (qx*qx + qy*qy + qz*qz)));
    }
    __syncthreads();

    const int lane = tid & 63;
    const int wave = tid >> 6;

    f32x2 acc2[4];
#pragma unroll
    for (int p = 0; p < 4; ++p) acc2[p] = PK2(0.0f);

#pragma unroll 1
    for (int ai = 0; ai < CH / 32; ++ai) {          // 8 a-iters, 8 a's per wave
        const int a4 = (ai * 32 + wave * 8) >> 2;   // index into f32x4 SoA
        f32x4 ax0 = sAX[a4], ax1 = sAX[a4 + 1];
        f32x4 ay0 = sAY[a4], ay1 = sAY[a4 + 1];
        f32x4 az0 = sAZ[a4], az1 = sAZ[a4 + 1];
        f32x4 a20 = sA2[a4], a21 = sA2[a4 + 1];
        // q-pairs as even-aligned subregisters of the x4 loads (no movs)
        f32x2 axp[4] = { ax0.xy, ax0.zw, ax1.xy, ax1.zw };
        f32x2 ayp[4] = { ay0.xy, ay0.zw, ay1.xy, ay1.zw };
        f32x2 azp[4] = { az0.xy, az0.zw, az1.xy, az1.zw };
        f32x2 a2p[4] = { a20.xy, a20.zw, a21.xy, a21.zw };

#pragma unroll
        for (int k = 0; k < CH / 64; ++k) {         // each lane: 1 b-point per k
            float4 b = sB[k * 64 + lane];           // one ds_read_b128 / 512 pairs
            f32x2 bxx = PK2(b.x);
            f32x2 byy = PK2(b.y);
            f32x2 bzz = PK2(b.z);
            f32x2 ebw = PK2(b.w);
#pragma unroll
            for (int p = 0; p < 4; ++p) {
                f32x2 arg = pkfma(axp[p], bxx,
                            pkfma(ayp[p], byy,
                            pkfma(azp[p], bzz, a2p[p])));
                acc2[p] = pk_exp2_mul_acc(arg, ebw, acc2[p]);
            }
        }
    }

    float tot = 0.0f;
#pragma unroll
    for (int p = 0; p < 4; ++p) tot += acc2[p].x + acc2[p].y;
#pragma unroll
    for (int off = 32; off > 0; off >>= 1)
        tot += __shfl_xor(tot, off, 64);

    if (lane == 0) red[wave] = tot;
    __syncthreads();
    if (tid == 0) {
        const float sa = (I < NXC) ? -1.0f : 1.0f;
        const float sb = (J < NXC) ? -1.0f : 1.0f;
        const float wt = (I == J) ? 1.0f : 2.0f;
        partials[bid] = (sa * sb * wt) * ((red[0] + red[1]) + (red[2] + red[3]));
    }
}

__global__ __launch_bounds__(256) void mmd_reduce(const float* __restrict__ partials,
                                                  float* __restrict__ out) {
    __shared__ float red[4];
    const int tid = threadIdx.x;
    float v = 0.0f;
    for (int i = tid; i < NB; i += 256) v += partials[i];
#pragma unroll
    for (int off = 32; off > 0; off >>= 1)
        v += __shfl_xor(v, off, 64);
    if ((tid & 63) == 0) red[tid >> 6] = v;
    __syncthreads();
    if (tid == 0)
        out[0] = ((red[0] + red[1]) + (red[2] + red[3])) * (1.0f / 67108864.0f);
}

extern "C" void kernel_launch(void* const* d_in, const int* in_sizes, int n_in,
                              void* d_out, int out_size, void* d_ws, size_t ws_size,
                              hipStream_t stream) {
    const float* x = (const float*)d_in[0];
    const float* w = (const float*)d_in[1];
    float* out      = (float*)d_out;
    float* partials = (float*)d_ws;   // NB floats = 8320 B

    hipLaunchKernelGGL(mmd_tri, dim3(NB), dim3(BLOCK), 0, stream, x, w, partials);
    hipLaunchKernelGGL(mmd_reduce, dim3(1), dim3(256), 0, stream, partials, out);
}

// Round 7
// 30.471 us; speedup vs baseline: 1.7528x; 1.7528x over previous
//
#include <hip/hip_runtime.h>
#include <hip/hip_bf16.h>

// MMD via symmetric triangular chunk decomposition, half-tile grid.
// u = [x; w] (16384 pts), s = [-1; +1]:
//   result = (sum_{i,j} s_i s_j k(u_i,u_j)) / 8192^2,   k = exp(-d2/2) = 2^(CEXP*d2)
// 64 chunks of 256 points; 2080 (I>=J) tiles; each tile split into TWO
// half-tiles (a-rows 0-127 / 128-255) -> 4160 blocks. Rationale: 2080 equal
// blocks over 1536 resident slots (6/CU) quantizes to batches 1536+544
// (eff 0.68, R3's hidden 32% tax); 4160 gives eff (4160/1536)/ceil = 0.90.
// Off-diagonal tiles weighted x2 (symmetry); diagonal x1.
//
// exp path: v_exp_f32 (R3-proven; ~16 issue-cy/wave64). Both VALU-poly
// attempts lost (R5 wrong by 800x its math bound -> compiler folding/UB;
// R6 correct but scratch-bound via the ldexp path, 19.6 MB WRITE_SIZE).
// Multiplicative fold (R6-proven correct): k = 2^(chain + a2c) * E_B with
// E_B = 2^(CEXP*|b|^2) staged; accumulate is pkfma(ev, E_B, acc).
// R4 lesson: keep __launch_bounds__(256,6); (256,8) forced spills.

#define NPTS     8192
#define CH       256
#define NC       64                 // 16384 / CH
#define NXC      32                 // chunks holding x (first half)
#define NB_TILES 2080               // NC*(NC+1)/2
#define NB_UNITS 4160               // 2 half-tiles per tile
#define BLOCK    256
#define CEXP     (-0.72134752044448169f)     // -1/(2 ln 2)
#define M2CEXP   (1.44269504088896340736f)   // -2*CEXP = 1/ln2

typedef float f32x2 __attribute__((ext_vector_type(2)));
typedef float f32x4 __attribute__((ext_vector_type(4)));

__device__ __forceinline__ f32x2 pkfma(f32x2 a, f32x2 b, f32x2 c) {
#if __has_builtin(__builtin_elementwise_fma)
    return __builtin_elementwise_fma(a, b, c);
#else
    f32x2 r; r.x = fmaf(a.x, b.x, c.x); r.y = fmaf(a.y, b.y, c.y); return r;
#endif
}

// Single-instruction 2^x (R3-proven).
__device__ __forceinline__ float fexp2(float v) {
#if __has_builtin(__builtin_amdgcn_exp2f)
    return __builtin_amdgcn_exp2f(v);
#else
    float r;
    asm("v_exp_f32 %0, %1" : "=v"(r) : "v"(v));
    return r;
#endif
}

#define PK2(v) ((f32x2){(v), (v)})

__global__ __launch_bounds__(BLOCK, 6) void mmd_tri(const float* __restrict__ x,
                                                    const float* __restrict__ w,
                                                    float* __restrict__ partials) {
    __shared__ f32x4  sAX[CH/4], sAY[CH/4], sAZ[CH/4], sA2[CH/4];  // A-form SoA
    __shared__ float4 sB[CH];                  // (bx, by, bz, E_B=2^(C|b|^2))
    __shared__ float  red[4];

    const int unit = blockIdx.x;
    const int tile = unit >> 1;                // triangular tile index
    const int half = unit & 1;                 // a-rows [half*128, half*128+128)

    // tile -> lower-triangle chunk pair (I, J), J <= I
    int I = (int)((sqrtf(8.0f * (float)tile + 1.0f) - 1.0f) * 0.5f);
    while ((I + 1) * (I + 2) / 2 <= tile) ++I;
    while (I * (I + 1) / 2 > tile) --I;
    const int J = tile - I * (I + 1) / 2;

    const int tid = threadIdx.x;
    {
        int gi = I * CH + tid;                      // chunks never straddle x/w
        const float* s = (gi < NPTS) ? x : w;
        int ii = gi & (NPTS - 1);
        float px = s[3*ii], py = s[3*ii+1], pz = s[3*ii+2];
        ((float*)sAX)[tid] = M2CEXP * px;
        ((float*)sAY)[tid] = M2CEXP * py;
        ((float*)sAZ)[tid] = M2CEXP * pz;
        ((float*)sA2)[tid] = CEXP * (px*px + py*py + pz*pz);

        int gj = J * CH + tid;
        const float* t = (gj < NPTS) ? x : w;
        int jj = gj & (NPTS - 1);
        float qx = t[3*jj], qy = t[3*jj+1], qz = t[3*jj+2];
        sB[tid] = make_float4(qx, qy, qz,
                              fexp2(CEXP * (qx*qx + qy*qy + qz*qz)));
    }
    __syncthreads();

    const int lane = tid & 63;
    const int wave = tid >> 6;

    f32x2 acc2[4];
#pragma unroll
    for (int p = 0; p < 4; ++p) acc2[p] = PK2(0.0f);

#pragma unroll 1
    for (int ai = half * 4; ai < half * 4 + 4; ++ai) {  // 4 a-iters (half tile)
        const int a4 = (ai * 32 + wave * 8) >> 2;   // index into f32x4 SoA
        f32x4 ax0 = sAX[a4], ax1 = sAX[a4 + 1];
        f32x4 ay0 = sAY[a4], ay1 = sAY[a4 + 1];
        f32x4 az0 = sAZ[a4], az1 = sAZ[a4 + 1];
        f32x4 a20 = sA2[a4], a21 = sA2[a4 + 1];
        // q-pairs as even-aligned subregisters of the x4 loads (no movs)
        f32x2 axp[4] = { ax0.xy, ax0.zw, ax1.xy, ax1.zw };
        f32x2 ayp[4] = { ay0.xy, ay0.zw, ay1.xy, ay1.zw };
        f32x2 azp[4] = { az0.xy, az0.zw, az1.xy, az1.zw };
        f32x2 a2p[4] = { a20.xy, a20.zw, a21.xy, a21.zw };

#pragma unroll
        for (int k = 0; k < CH / 64; ++k) {         // each lane: 1 b-point per k
            float4 b = sB[k * 64 + lane];           // one ds_read_b128 / 512 pairs
            f32x2 bxx = PK2(b.x);
            f32x2 byy = PK2(b.y);
            f32x2 bzz = PK2(b.z);
            f32x2 ebw = PK2(b.w);
#pragma unroll
            for (int p = 0; p < 4; ++p) {
                f32x2 arg = pkfma(axp[p], bxx,
                            pkfma(ayp[p], byy,
                            pkfma(azp[p], bzz, a2p[p])));
                f32x2 ev;
                ev.x = fexp2(arg.x);
                ev.y = fexp2(arg.y);
                acc2[p] = pkfma(ev, ebw, acc2[p]);  // k = 2^arg * E_B, folded
            }
        }
    }

    float tot = 0.0f;
#pragma unroll
    for (int p = 0; p < 4; ++p) tot += acc2[p].x + acc2[p].y;
#pragma unroll
    for (int off = 32; off > 0; off >>= 1)
        tot += __shfl_xor(tot, off, 64);

    if (lane == 0) red[wave] = tot;
    __syncthreads();
    if (tid == 0) {
        const float sa = (I < NXC) ? -1.0f : 1.0f;
        const float sb = (J < NXC) ? -1.0f : 1.0f;
        const float wt = (I == J) ? 1.0f : 2.0f;
        partials[unit] = (sa * sb * wt) * ((red[0] + red[1]) + (red[2] + red[3]));
    }
}

__global__ __launch_bounds__(256) void mmd_reduce(const float* __restrict__ partials,
                                                  float* __restrict__ out) {
    __shared__ float red[4];
    const int tid = threadIdx.x;
    float v = 0.0f;
    for (int i = tid; i < NB_UNITS; i += 256) v += partials[i];
#pragma unroll
    for (int off = 32; off > 0; off >>= 1)
        v += __shfl_xor(v, off, 64);
    if ((tid & 63) == 0) red[tid >> 6] = v;
    __syncthreads();
    if (tid == 0)
        out[0] = ((red[0] + red[1]) + (red[2] + red[3])) * (1.0f / 67108864.0f);
}

extern "C" void kernel_launch(void* const* d_in, const int* in_sizes, int n_in,
                              void* d_out, int out_size, void* d_ws, size_t ws_size,
                              hipStream_t stream) {
    const float* x = (const float*)d_in[0];
    const float* w = (const float*)d_in[1];
    float* out      = (float*)d_out;
    float* partials = (float*)d_ws;   // NB_UNITS floats = 16640 B

    hipLaunchKernelGGL(mmd_tri, dim3(NB_UNITS), dim3(BLOCK), 0, stream, x, w, partials);
    hipLaunchKernelGGL(mmd_reduce, dim3(1), dim3(256), 0, stream, partials, out);
}